// Round 5
// baseline (32.800 us; speedup 1.0000x reference)
//
#include <hip/hip_runtime.h>
#include <math.h>

struct V2 { float x, y; };

#define NT 256

// angle class matching atan2 range ordering: 0: y<0 (-pi,0); 1: y==0,x>=0 {0};
// 2: y>0 (0,pi); 3: y==0,x<0 {pi}
__device__ __forceinline__ int ang_class(float x, float y) {
    return (y < 0.f) ? 0 : ((y > 0.f) ? 2 : ((x >= 0.f) ? 1 : 3));
}

// Stable ascending argsort of 4 points by exact atan2 ordering around centroid.
// 6 pairwise comparisons; double products of float32 are exact.
__device__ __forceinline__ void angle_sort4(float4 lo, float4 hi, V2 out[4]) {
    V2 p[4];
    p[0].x = lo.x; p[0].y = lo.y;
    p[1].x = lo.z; p[1].y = lo.w;
    p[2].x = hi.x; p[2].y = hi.y;
    p[3].x = hi.z; p[3].y = hi.w;
    float cx = (((p[0].x + p[1].x) + p[2].x) + p[3].x) * 0.25f;
    float cy = (((p[0].y + p[1].y) + p[2].y) + p[3].y) * 0.25f;
    float rx[4], ry[4]; int cls[4];
#pragma unroll
    for (int i = 0; i < 4; i++) {
        rx[i] = p[i].x - cx; ry[i] = p[i].y - cy;
        cls[i] = ang_class(rx[i], ry[i]);
    }
    int rank[4] = {0, 0, 0, 0};
#pragma unroll
    for (int i = 0; i < 4; i++) {
#pragma unroll
        for (int j = i + 1; j < 4; j++) {
            int cd = cls[i] - cls[j];
            // cr > 0 -> ang_i < ang_j ; cr == 0 for the y==0 classes (exact)
            double cr = (double)rx[i] * (double)ry[j] - (double)ry[i] * (double)rx[j];
            bool gt = (cd > 0) || (cd == 0 && cr < 0.0);  // ang_i > ang_j
            rank[i] += gt ? 1 : 0;
            rank[j] += gt ? 0 : 1;   // includes equal-angle stable tie (i<j)
        }
    }
#pragma unroll
    for (int k = 0; k < 4; k++) {
#pragma unroll
        for (int i = 0; i < 4; i++) {
            if (rank[i] == k) out[k] = p[i];
        }
    }
}

// One Sutherland-Hodgman round, IN-PLACE in LDS: reads 8 slots of this thread's
// column into registers, clips by edge A->B, compacts back into same column.
__device__ __forceinline__ int clip_mid(float2 (*buf)[NT], V2 A, V2 B,
                                        int nv, int tid)
{
    float ex = B.x - A.x, ey = B.y - A.y;
    V2 p[8]; float d[8];
#pragma unroll
    for (int s = 0; s < 8; s++) {
        float2 v = buf[s][tid];
        p[s].x = v.x; p[s].y = v.y;
        d[s] = ex * (v.y - A.y) - ey * (v.x - A.x);
    }
    int cnt = 0;
#pragma unroll
    for (int idx = 0; idx < 8; idx++) {
        // next vertex: replicates poly[(idx+1) % max(nv,1)] with JAX index-clamp
        V2 nx; float dn;
        if (idx == 7) {
            bool w = (nv == 8);          // nv>8 -> index 8 clamps to slot 7 (self)
            nx.x = w ? p[0].x : p[7].x;
            nx.y = w ? p[0].y : p[7].y;
            dn   = w ? d[0]   : d[7];
        } else {
            bool w = ((idx + 1) == nv);
            nx.x = w ? p[0].x : p[idx + 1].x;
            nx.y = w ? p[0].y : p[idx + 1].y;
            dn   = w ? d[0]   : d[idx + 1];
        }
        bool active = idx < nv;
        bool in_cur = d[idx] >= 0.f;
        bool in_nxt = dn >= 0.f;
        float den = d[idx] - dn;
        den = (fabsf(den) < 1e-12f) ? 1e-12f : den;
        float t = __fdividef(d[idx], den);
        float ix = p[idx].x + t * (nx.x - p[idx].x);
        float iy = p[idx].y + t * (nx.y - p[idx].y);
        bool v0 = active && in_cur;
        bool v1 = active && (in_cur != in_nxt);
        if (v0 && cnt < 8) buf[cnt][tid] = make_float2(p[idx].x, p[idx].y);
        cnt += v0 ? 1 : 0;
        if (v1 && cnt < 8) buf[cnt][tid] = make_float2(ix, iy);
        cnt += v1 ? 1 : 0;
    }
    return cnt;   // unclamped count, like the reference
}

// Final round: clip and accumulate the shoelace over emitted points directly
// (no LDS writes, no re-read). Emission order == slot order, and the wrap term
// is added last == reference's term at idx nv-1; identical FP sum order.
__device__ __forceinline__ float clip_final(const float2 (*buf)[NT], V2 A, V2 B,
                                            int nv, int tid)
{
    float ex = B.x - A.x, ey = B.y - A.y;
    V2 p[8]; float d[8];
#pragma unroll
    for (int s = 0; s < 8; s++) {
        float2 v = buf[s][tid];
        p[s].x = v.x; p[s].y = v.y;
        d[s] = ex * (v.y - A.y) - ey * (v.x - A.x);
    }
    int cnt = 0;
    float sx = 0.f;
    float fx = 0.f, fy = 0.f;   // first kept point
    float px = 0.f, py = 0.f;   // prev kept point (slot <= 7)
#pragma unroll
    for (int idx = 0; idx < 8; idx++) {
        V2 nx; float dn;
        if (idx == 7) {
            bool w = (nv == 8);
            nx.x = w ? p[0].x : p[7].x;
            nx.y = w ? p[0].y : p[7].y;
            dn   = w ? d[0]   : d[7];
        } else {
            bool w = ((idx + 1) == nv);
            nx.x = w ? p[0].x : p[idx + 1].x;
            nx.y = w ? p[0].y : p[idx + 1].y;
            dn   = w ? d[0]   : d[idx + 1];
        }
        bool active = idx < nv;
        bool in_cur = d[idx] >= 0.f;
        bool in_nxt = dn >= 0.f;
        float den = d[idx] - dn;
        den = (fabsf(den) < 1e-12f) ? 1e-12f : den;
        float t = __fdividef(d[idx], den);
        float ix = p[idx].x + t * (nx.x - p[idx].x);
        float iy = p[idx].y + t * (nx.y - p[idx].y);
        bool v0 = active && in_cur;
        bool v1 = active && (in_cur != in_nxt);
        // emit cur
        {
            bool w0 = (cnt == 0), wl = (cnt <= 7);
            float qx = p[idx].x, qy = p[idx].y;
            if (v0) {
                fx = w0 ? qx : fx; fy = w0 ? qy : fy;
                sx += (!w0 && wl) ? (px * qy - qx * py) : 0.f;
                px = wl ? qx : px; py = wl ? qy : py;
            }
            cnt += v0 ? 1 : 0;
        }
        // emit crossing
        {
            bool w0 = (cnt == 0), wl = (cnt <= 7);
            if (v1) {
                fx = w0 ? ix : fx; fy = w0 ? iy : fy;
                sx += (!w0 && wl) ? (px * iy - ix * py) : 0.f;
                px = wl ? ix : px; py = wl ? iy : py;
            }
            cnt += v1 ? 1 : 0;
        }
    }
    // wrap term (ref: idx nv-1 pairs poly[0]); nv>8 -> slot7 pairs itself (0)
    if (cnt > 0 && cnt <= 8) sx += px * fy - fx * py;
    return 0.5f * fabsf(sx);
}

__global__ __launch_bounds__(256, 8) void poly_iou_kernel(
    const float* __restrict__ preds, const float* __restrict__ targets,
    float* __restrict__ out, int n)
{
    __shared__ float2 buf[8][NT];   // 16 KB: per-thread 8-slot scratch column
    int tid = threadIdx.x;
    int gid = blockIdx.x * NT + tid;
    if (gid >= n) return;

    const float4* p4 = reinterpret_cast<const float4*>(preds);
    const float4* t4 = reinterpret_cast<const float4*>(targets);
    float4 a0 = p4[2 * gid], a1 = p4[2 * gid + 1];
    float4 b0 = t4[2 * gid], b1 = t4[2 * gid + 1];

    V2 P[4], T[4];
    angle_sort4(a0, a1, P);
    angle_sort4(b0, b1, T);

    // ---- edge 0 (nv=4 compile-time): registers -> buf ----
    int nv;
    {
        float ex = T[1].x - T[0].x, ey = T[1].y - T[0].y;
        float dd[4];
#pragma unroll
        for (int k = 0; k < 4; k++)
            dd[k] = ex * (P[k].y - T[0].y) - ey * (P[k].x - T[0].x);
        int cnt = 0;
#pragma unroll
        for (int idx = 0; idx < 4; idx++) {
            int j = (idx + 1) & 3;
            bool in_cur = dd[idx] >= 0.f;
            bool in_nxt = dd[j] >= 0.f;
            float den = dd[idx] - dd[j];
            den = (fabsf(den) < 1e-12f) ? 1e-12f : den;
            float t = __fdividef(dd[idx], den);
            float ix = P[idx].x + t * (P[j].x - P[idx].x);
            float iy = P[idx].y + t * (P[j].y - P[idx].y);
            bool v1 = (in_cur != in_nxt);
            if (in_cur) buf[cnt][tid] = make_float2(P[idx].x, P[idx].y);
            cnt += in_cur ? 1 : 0;
            if (v1) buf[cnt][tid] = make_float2(ix, iy);
            cnt += v1 ? 1 : 0;
        }
        nv = cnt;   // <= 8 from 4 vertices, no drop possible
    }

    // ---- edges 1..2 in place; edge 3 fused with shoelace ----
    nv = clip_mid(buf, T[1], T[2], nv, tid);
    nv = clip_mid(buf, T[2], T[3], nv, tid);
    float inter = clip_final(buf, T[3], T[0], nv, tid);

    // ---- convex hull (gift wrap, fully unrolled) of the 8 sorted points ----
    V2 h[8];
#pragma unroll
    for (int k = 0; k < 4; k++) { h[k] = P[k]; h[4 + k] = T[k]; }

    int start = 0; V2 vs = h[0];
#pragma unroll
    for (int k = 1; k < 8; k++) {           // first-index argmin of y
        bool b = h[k].y < vs.y;
        start = b ? k : start;
        vs.x  = b ? h[k].x : vs.x;
        vs.y  = b ? h[k].y : vs.y;
    }

    V2 pc = vs; int cur = start; bool done = false; float harea = 0.f;
#pragma unroll
    for (int s = 0; s < 8; s++) {
        // most-clockwise ray from pc; farthest on collinear; first index on tie.
        // bx=by=0 start: first valid k takes via (c==0 && d2>bd), bd=0.
        int best = cur;
        float bx = 0.f, by = 0.f, bd = 0.f, px = pc.x, py = pc.y;
#pragma unroll
        for (int k = 0; k < 8; k++) {
            float rx = h[k].x - pc.x, ry = h[k].y - pc.y;
            float d2 = rx * rx + ry * ry;
            bool ok = d2 > 1e-12f;
            float c = bx * ry - by * rx;    // cross(best, k)
            bool take = ok && ((c < 0.f) || ((c == 0.f) && (d2 > bd)));
            best = take ? k : best;
            bx = take ? rx : bx; by = take ? ry : by; bd = take ? d2 : bd;
            px = take ? h[k].x : px; py = take ? h[k].y : py;
        }
        int nxt = done ? cur : best;
        V2 pv;
        pv.x = done ? pc.x : px;
        pv.y = done ? pc.y : py;
        harea += pc.x * pv.y - pv.x * pc.y;  // stay-steps add exact 0
        done = done || (nxt == start);
        pc = pv; cur = nxt;
    }
    harea += pc.x * vs.y - vs.x * pc.y;     // closure
    harea = 0.5f * fabsf(harea);

    float iou = (harea > 1e-12f) ? (inter / fmaxf(harea, 1e-12f)) : 0.f;
    out[gid] = 1.f - iou;
}

extern "C" void kernel_launch(void* const* d_in, const int* in_sizes, int n_in,
                              void* d_out, int out_size, void* d_ws, size_t ws_size,
                              hipStream_t stream) {
    const float* preds = (const float*)d_in[0];
    const float* targets = (const float*)d_in[1];
    float* out = (float*)d_out;
    int n = in_sizes[0] / 8;
    int block = NT;
    int grid = (n + block - 1) / block;
    hipLaunchKernelGGL(poly_iou_kernel, dim3(grid), dim3(block), 0, stream,
                       preds, targets, out, n);
}